// Round 3
// baseline (228.846 us; speedup 1.0000x reference)
//
#include <hip/hip_runtime.h>
#include <math.h>

#define NBB 128
#define NAA 5
#define NCC 80
#define NHH 28
#define NWW 28
#define NTT 50
#define CH  85            // 5 + NC
#define HW  784           // NH*NW
#define CELLS 3920        // NA*NH*NW

__constant__ float c_AW[5] = {2.8f, 5.1f, 6.4f, 9.2f, 14.1f};
__constant__ float c_AH[5] = {4.8f, 10.2f, 16.3f, 19.8f, 23.7f};

__device__ __forceinline__ float sigmoidf_(float x) {
    return 1.0f / (1.0f + __expf(-x));
}

__device__ __forceinline__ float smooth_l1(float d) {
    float ad = fabsf(d);
    return (ad < 1.0f) ? 0.5f * d * d : ad - 0.5f;
}

// ---------------------------------------------------------------------------
// Fused kernel v3: grid (4, NB), block 256 (4 waves), 4 CELLS PER THREAD.
//
// R2 model: stage-2's 50-iter loop was LDS-pipe-bound (3 broadcasts/iter =
// ~26 LDS-cyc; ~40K LDS cycles/CU = ~16 us). v3 cuts LDS traffic two ways:
//  (a) 4 cells/thread: one boxS b128 + s6 b32 read per j serves 4 cells.
//  (b) assigned-cell scan (b64 + 3 VALU per j) replaced by LDS scatter grid
//      tcA[3920]: init -1, dedup'd last-winner scatter, ONE b32 gather/cell.
// Stage 3 (focal/coord per record) runs BEFORE stage 2 so its gathered VMEM
// overlaps the j-loop; 4 records per wave via k-loop (4bx*4w*4k=64 >= 50).
// ---------------------------------------------------------------------------
__global__ __launch_bounds__(256) void region_loss_fused(
    const float* __restrict__ out, const float* __restrict__ tgt,
    float* __restrict__ d_out)
{
    __shared__ float  tcA[CELLS];     // scatter grid: tconf of last-winner, else -1
    __shared__ float4 boxS[NTT];      // (L, R, T, B)
    __shared__ float  s6[NTT];        // 0.375 * gt area
    __shared__ int    rCell[NTT];
    __shared__ float  rTx[NTT], rTy[NTT], rTw[NTT], rTh[NTT];
    __shared__ int    rCls[NTT];
    __shared__ unsigned char rActive[NTT];
    __shared__ float  wred[4];

    const int b   = blockIdx.y;
    const int bx  = blockIdx.x;
    const int tid = threadIdx.x;

    // ---- init scatter grid ----
    for (int i = tid; i < CELLS; i += 256) tcA[i] = -1.0f;

    // ---- Stage 1: per-target prep (threads 0..49) ----
    float myTc = 0.0f;
    int   myCell = -1;
    if (tid < NTT) {
        const float* tp = tgt + b * NTT * 5 + tid * 5;
        float cls = tp[0];
        float gx = tp[1] * NWW;
        float gy = tp[2] * NHH;
        float gw = tp[3] * NWW;
        float gh = tp[4] * NHH;
        float ga = gw * gh;

        boxS[tid] = make_float4(gx - gw * 0.5f, gx + gw * 0.5f,
                                gy - gh * 0.5f, gy + gh * 0.5f);
        s6[tid] = 0.375f * ga;        // 0.6/1.6 = 0.375 exactly

        // best anchor: first max wins
        int best = 0; float bestI = -1.0f;
        #pragma unroll
        for (int a = 0; a < 5; ++a) {
            float inter = fminf(gw, c_AW[a]) * fminf(gh, c_AH[a]);
            float uni   = ga + c_AW[a] * c_AH[a] - inter;
            float iou   = inter / uni;
            if (iou > bestI) { bestI = iou; best = a; }
        }
        int gi = (int)floorf(gx);
        int gj = (int)floorf(gy);
        int cell = (best * NHH + gj) * NWW + gi;

        const float* op = out + ((size_t)(b * NAA + best) * CH) * HW + gj * NWW + gi;
        float px = sigmoidf_(op[0])      + (float)gi;
        float py = sigmoidf_(op[HW])     + (float)gj;
        float pw = __expf(op[2 * HW]) * c_AW[best];
        float ph = __expf(op[3 * HW]) * c_AH[best];

        float mx = fminf(px - pw * 0.5f, gx - gw * 0.5f);
        float Mx = fmaxf(px + pw * 0.5f, gx + gw * 0.5f);
        float my = fminf(py - ph * 0.5f, gy - gh * 0.5f);
        float My = fmaxf(py + ph * 0.5f, gy + gh * 0.5f);
        float cw  = pw + gw - (Mx - mx);
        float chh = ph + gh - (My - my);
        float inter = (cw > 0.f && chh > 0.f) ? cw * chh : 0.f;
        float uni   = pw * ph + ga - inter;

        myCell = cell;
        myTc   = inter / uni;
        rCell[tid] = cell;
        rTx[tid]   = gx - (float)gi;
        rTy[tid]   = gy - (float)gj;
        rTw[tid]   = __logf(gw / c_AW[best]);
        rTh[tid]   = __logf(gh / c_AH[best]);
        rCls[tid]  = (int)cls;
    }
    __syncthreads();

    // ---- dedup (last-write-wins) + scatter tconf into grid ----
    if (tid < NTT) {
        unsigned char active = 1;
        for (int t2 = tid + 1; t2 < NTT; ++t2)
            if (rCell[t2] == myCell) active = 0;   // later record wins
        rActive[tid] = active;
        if (active) tcA[myCell] = myTc;            // unique per cell: race-free
    }
    __syncthreads();

    // ---- Stage 3 first: assigned-record loss, 4 records per wave ----
    const int wave = tid >> 6;
    const int lane = tid & 63;
    float contrib = 0.0f;

    #pragma unroll
    for (int k = 0; k < 4; ++k) {
        const int j = (bx * 4 + wave) + 16 * k;    // 64 slots >= NTT, unique
        if (j < NTT && rActive[j]) {
            int rc = rCell[j];
            int a  = rc / HW;
            int hw = rc - a * HW;
            const float* op = out + ((size_t)(b * NAA + a) * CH) * HW + hw;

            float l0  = op[(5 + lane) * HW];
            float l1c = (lane < 16) ? op[(5 + 64 + lane) * HW] : -INFINITY;

            float m = fmaxf(l0, l1c);
            for (int o = 32; o >= 1; o >>= 1) m = fmaxf(m, __shfl_xor(m, o));
            float s = __expf(l0 - m) + ((lane < 16) ? __expf(l1c - m) : 0.0f);
            for (int o = 32; o >= 1; o >>= 1) s += __shfl_xor(s, o);

            int t = rCls[j];                       // wave-uniform
            float lt = (t < 64) ? __shfl(l0, t) : __shfl(l1c, t - 64);
            float logpt = lt - m - __logf(s);
            float pt = __expf(logpt);
            float focal = -(1.0f - pt) * (1.0f - pt) * logpt;

            if (lane == 0) {
                float x = sigmoidf_(op[0]);
                float y = sigmoidf_(op[HW]);
                float w = op[2 * HW];
                float h = op[3 * HW];
                contrib += focal +
                           0.5f * (smooth_l1(x - rTx[j]) + smooth_l1(y - rTy[j]) +
                                   smooth_l1(w - rTw[j]) + smooth_l1(h - rTh[j]));
            }
        }
    }

    // ---- Stage 2: conf loss, 4 cells per thread ----
    float l1c_[4], r1c_[4], t1c_[4], b1c_[4], c1c_[4], confc_[4];
    bool  fl_[4];

    #pragma unroll
    for (int k = 0; k < 4; ++k) {
        const int cell = bx * 1024 + (k << 8) + tid;
        fl_[k] = false;
        if (cell < CELLS) {
            int a  = cell / HW;
            int hw = cell - a * HW;
            int wi = hw % NWW;
            int hj = hw / NWW;
            const float* op = out + ((size_t)(b * NAA + a) * CH) * HW + hw;

            float px   = sigmoidf_(op[0])  + (float)wi;
            float py   = sigmoidf_(op[HW]) + (float)hj;
            float pw   = __expf(op[2 * HW]) * c_AW[a];
            float ph   = __expf(op[3 * HW]) * c_AH[a];
            confc_[k]  = sigmoidf_(op[4 * HW]);

            l1c_[k] = px - pw * 0.5f;  r1c_[k] = px + pw * 0.5f;
            t1c_[k] = py - ph * 0.5f;  b1c_[k] = py + ph * 0.5f;
            c1c_[k] = 0.375f * (pw * ph);
        } else {
            // inert: intersection always 0, threshold unreachable
            l1c_[k] = 1e30f;  r1c_[k] = -1e30f;
            t1c_[k] = 1e30f;  b1c_[k] = -1e30f;
            c1c_[k] = 1e30f;  confc_[k] = 0.0f;
        }
    }

    #pragma unroll 5
    for (int j = 0; j < NTT; ++j) {
        float4 bxj = boxS[j];                      // one ds_read_b128 / 4 cells
        float  sj  = s6[j];                        // one ds_read_b32  / 4 cells
        #pragma unroll
        for (int k = 0; k < 4; ++k) {
            float cw  = fminf(r1c_[k], bxj.y) - fmaxf(l1c_[k], bxj.x);
            float ch2 = fminf(b1c_[k], bxj.w) - fmaxf(t1c_[k], bxj.z);
            float inter = fmaxf(cw, 0.f) * fmaxf(ch2, 0.f);
            fl_[k] = fl_[k] || (inter > c1c_[k] + sj);   // iou > 0.6
        }
    }

    float term = 0.0f;
    #pragma unroll
    for (int k = 0; k < 4; ++k) {
        const int cell = bx * 1024 + (k << 8) + tid;
        if (cell < CELLS) {
            float tc = tcA[cell];                  // one b32 gather per cell
            if (tc > -0.5f) {
                float d = confc_[k] - tc; term += 2.5f * d * d;
            } else if (!fl_[k]) {
                term += 0.5f * confc_[k] * confc_[k];
            }
        }
    }

    // ---- reduction: wave shuffle + 4-slot LDS + single atomic ----
    float v = term + contrib;                      // contrib nonzero only on lane 0
    #pragma unroll
    for (int o = 32; o >= 1; o >>= 1) v += __shfl_xor(v, o);
    if (lane == 0) wred[wave] = v;
    __syncthreads();
    if (tid == 0)
        atomicAdd(d_out, wred[0] + wred[1] + wred[2] + wred[3]);
}

extern "C" void kernel_launch(void* const* d_in, const int* in_sizes, int n_in,
                              void* d_out, int out_size, void* d_ws, size_t ws_size,
                              hipStream_t stream) {
    const float* out_p = (const float*)d_in[0];   // (128, 425, 28, 28)
    const float* tgt_p = (const float*)d_in[1];   // (128, 250)
    float* loss = (float*)d_out;

    hipMemsetAsync(loss, 0, (size_t)out_size * sizeof(float), stream);

    region_loss_fused<<<dim3(4, NBB), dim3(256), 0, stream>>>(
        out_p, tgt_p, loss);
}

// Round 5
// 227.168 us; speedup vs baseline: 1.0074x; 1.0074x over previous
//
#include <hip/hip_runtime.h>
#include <math.h>

#define NBB 128
#define NAA 5
#define NCC 80
#define NHH 28
#define NWW 28
#define NTT 50
#define CH  85            // 5 + NC
#define HW  784           // NH*NW
#define CELLS 3920        // NA*NH*NW

__constant__ float c_AW[5] = {2.8f, 5.1f, 6.4f, 9.2f, 14.1f};
__constant__ float c_AH[5] = {4.8f, 10.2f, 16.3f, 19.8f, 23.7f};

__device__ __forceinline__ float sigmoidf_(float x) {
    return 1.0f / (1.0f + __expf(-x));
}

__device__ __forceinline__ float smooth_l1(float d) {
    float ad = fabsf(d);
    return (ad < 1.0f) ? 0.5f * d * d : ad - 0.5f;
}

// broadcast lane l's register value to all lanes (v_readlane -> SGPR; no LDS)
__device__ __forceinline__ float rdlane(float v, int l) {
    return __uint_as_float(__builtin_amdgcn_readlane(__float_as_uint(v), l));
}

// ---------------------------------------------------------------------------
// Fused kernel v4: grid (4, NB), block 1024 (16 waves) -> 8192 waves (v2's
// proven occupancy), but the stage-2 j-loop is now LDS-FREE:
//  - each lane holds target-(lane)'s (L,R,T,B, 0.375*area) in 5 VGPRs,
//    loaded once per wave from LDS staging;
//  - the 50-iter loop broadcasts lane j via v_readlane (VALU pipe, SGPR
//    result) -- replaces v2's b128+b32+b64 LDS broadcasts per iteration.
//  - assigned-cell scan replaced by tcA scatter grid (init -1, dedup'd
//    last-winner scatter, ONE b32 gather per cell) -- validated in v3.
// Stage 3 stays v2-style: one record per wave (4bx*16w = 64 slots >= 50).
// ---------------------------------------------------------------------------
__global__ __launch_bounds__(1024) void region_loss_fused(
    const float* __restrict__ out, const float* __restrict__ tgt,
    float* __restrict__ d_out)
{
    __shared__ float tcA[CELLS];      // scatter grid: tconf of last-winner, else -1
    __shared__ float Lb[NTT], Rb[NTT], Tb[NTT], Bb[NTT], Sb[NTT];
    __shared__ int   rCell[NTT];
    __shared__ float rTx[NTT], rTy[NTT], rTw[NTT], rTh[NTT];
    __shared__ int   rCls[NTT];
    __shared__ unsigned char rActive[NTT];
    __shared__ float wred[16];

    const int b   = blockIdx.y;
    const int bx  = blockIdx.x;
    const int tid = threadIdx.x;

    // ---- init scatter grid (4 iters/thread) ----
    for (int i = tid; i < CELLS; i += 1024) tcA[i] = -1.0f;

    // ---- Stage 1: per-target prep (threads 0..49) ----
    float myTc = 0.0f;
    int   myCell = -1;
    if (tid < NTT) {
        const float* tp = tgt + b * NTT * 5 + tid * 5;
        float cls = tp[0];
        float gx = tp[1] * NWW;
        float gy = tp[2] * NHH;
        float gw = tp[3] * NWW;
        float gh = tp[4] * NHH;
        float ga = gw * gh;

        Lb[tid] = gx - gw * 0.5f;
        Rb[tid] = gx + gw * 0.5f;
        Tb[tid] = gy - gh * 0.5f;
        Bb[tid] = gy + gh * 0.5f;
        Sb[tid] = 0.375f * ga;        // 0.6/1.6 = 0.375 exactly

        // best anchor: first max wins
        int best = 0; float bestI = -1.0f;
        #pragma unroll
        for (int a = 0; a < 5; ++a) {
            float inter = fminf(gw, c_AW[a]) * fminf(gh, c_AH[a]);
            float uni   = ga + c_AW[a] * c_AH[a] - inter;
            float iou   = inter / uni;
            if (iou > bestI) { bestI = iou; best = a; }
        }
        int gi = (int)floorf(gx);
        int gj = (int)floorf(gy);
        int cell = (best * NHH + gj) * NWW + gi;

        const float* op = out + ((size_t)(b * NAA + best) * CH) * HW + gj * NWW + gi;
        float px = sigmoidf_(op[0])      + (float)gi;
        float py = sigmoidf_(op[HW])     + (float)gj;
        float pw = __expf(op[2 * HW]) * c_AW[best];
        float ph = __expf(op[3 * HW]) * c_AH[best];

        float mx = fminf(px - pw * 0.5f, gx - gw * 0.5f);
        float Mx = fmaxf(px + pw * 0.5f, gx + gw * 0.5f);
        float my = fminf(py - ph * 0.5f, gy - gh * 0.5f);
        float My = fmaxf(py + ph * 0.5f, gy + gh * 0.5f);
        float cw  = pw + gw - (Mx - mx);
        float chh = ph + gh - (My - my);
        float inter = (cw > 0.f && chh > 0.f) ? cw * chh : 0.f;
        float uni   = pw * ph + ga - inter;

        myCell = cell;
        myTc   = inter / uni;
        rCell[tid] = cell;
        rTx[tid]   = gx - (float)gi;
        rTy[tid]   = gy - (float)gj;
        rTw[tid]   = __logf(gw / c_AW[best]);
        rTh[tid]   = __logf(gh / c_AH[best]);
        rCls[tid]  = (int)cls;
    }
    __syncthreads();

    // ---- dedup (last-write-wins) + scatter tconf into grid ----
    if (tid < NTT) {
        unsigned char active = 1;
        for (int t2 = tid + 1; t2 < NTT; ++t2)
            if (rCell[t2] == myCell) active = 0;   // later record wins
        rActive[tid] = active;
        if (active) tcA[myCell] = myTc;            // unique per cell: race-free
    }
    __syncthreads();

    // ---- per-wave: pull the 50 targets into lane registers (5 b32, once) ----
    const int wave = tid >> 6;
    const int lane = tid & 63;
    const int ll   = (lane < NTT) ? lane : 0;
    const float tL = Lb[ll], tR = Rb[ll], tT = Tb[ll], tB = Bb[ll], tS = Sb[ll];

    // ---- Stage 2: conf loss, 1 cell/thread, LDS-free j-loop ----
    const int cell = bx * 1024 + tid;
    const bool valid = (cell < CELLS);
    float term = 0.0f;

    float l1, r1, t1, b1, c1, conf;
    if (valid) {
        int a  = cell / HW;
        int hw = cell - a * HW;
        int wi = hw % NWW;
        int hj = hw / NWW;
        const float* op = out + ((size_t)(b * NAA + a) * CH) * HW + hw;

        float px = sigmoidf_(op[0])  + (float)wi;
        float py = sigmoidf_(op[HW]) + (float)hj;
        float pw = __expf(op[2 * HW]) * c_AW[a];
        float ph = __expf(op[3 * HW]) * c_AH[a];
        conf     = sigmoidf_(op[4 * HW]);

        l1 = px - pw * 0.5f;  r1 = px + pw * 0.5f;
        t1 = py - ph * 0.5f;  b1 = py + ph * 0.5f;
        c1 = 0.375f * (pw * ph);
    } else {
        l1 = 1e30f;  r1 = -1e30f;   // empty box: inter always 0
        t1 = 1e30f;  b1 = -1e30f;
        c1 = 1e30f;  conf = 0.0f;   // threshold unreachable
    }

    bool flag = false;
    #pragma unroll
    for (int j = 0; j < NTT; ++j) {
        float Lj = rdlane(tL, j);
        float Rj = rdlane(tR, j);
        float Tj = rdlane(tT, j);
        float Bj = rdlane(tB, j);
        float Sj = rdlane(tS, j);
        float cw  = fminf(r1, Rj) - fmaxf(l1, Lj);
        float ch2 = fminf(b1, Bj) - fmaxf(t1, Tj);
        float inter = fmaxf(cw, 0.f) * fmaxf(ch2, 0.f);
        flag = flag || (inter > c1 + Sj);          // iou > 0.6, division-free
    }

    if (valid) {
        float tc = tcA[cell];                      // one b32 gather per cell
        if (tc > -0.5f) {
            float d = conf - tc; term = 2.5f * d * d;
        } else if (!flag) {
            term = 0.5f * conf * conf;
        }
    }

    // ---- Stage 3: assigned-record loss, one record per wave ----
    const int j3 = bx * 16 + wave;                 // 4*16 = 64 slots >= NTT
    float contrib = 0.0f;

    if (j3 < NTT && rActive[j3]) {
        int rc = rCell[j3];
        int a  = rc / HW;
        int hw = rc - a * HW;
        const float* op = out + ((size_t)(b * NAA + a) * CH) * HW + hw;

        // class logits: lane -> c=lane, plus c=64+lane for lane<16
        float l0  = op[(5 + lane) * HW];
        float l1c = (lane < 16) ? op[(5 + 64 + lane) * HW] : -INFINITY;

        float m = fmaxf(l0, l1c);
        for (int o = 32; o >= 1; o >>= 1) m = fmaxf(m, __shfl_xor(m, o));
        float s = __expf(l0 - m) + ((lane < 16) ? __expf(l1c - m) : 0.0f);
        for (int o = 32; o >= 1; o >>= 1) s += __shfl_xor(s, o);

        int t = rCls[j3];                          // wave-uniform
        float lt = (t < 64) ? __shfl(l0, t) : __shfl(l1c, t - 64);
        float logpt = lt - m - __logf(s);
        float pt = __expf(logpt);
        float focal = -(1.0f - pt) * (1.0f - pt) * logpt;

        if (lane == 0) {
            float x = sigmoidf_(op[0]);
            float y = sigmoidf_(op[HW]);
            float w = op[2 * HW];
            float h = op[3 * HW];
            contrib = focal +
                      0.5f * (smooth_l1(x - rTx[j3]) + smooth_l1(y - rTy[j3]) +
                              smooth_l1(w - rTw[j3]) + smooth_l1(h - rTh[j3]));
        }
    }

    // ---- reduction: wave shuffle + 16-slot LDS + single atomic ----
    float v = term + contrib;                      // contrib nonzero only on lane 0
    #pragma unroll
    for (int o = 32; o >= 1; o >>= 1) v += __shfl_xor(v, o);
    if (lane == 0) wred[wave] = v;
    __syncthreads();
    if (tid == 0) {
        float s = 0.0f;
        #pragma unroll
        for (int w2 = 0; w2 < 16; ++w2) s += wred[w2];
        atomicAdd(d_out, s);
    }
}

extern "C" void kernel_launch(void* const* d_in, const int* in_sizes, int n_in,
                              void* d_out, int out_size, void* d_ws, size_t ws_size,
                              hipStream_t stream) {
    const float* out_p = (const float*)d_in[0];   // (128, 425, 28, 28)
    const float* tgt_p = (const float*)d_in[1];   // (128, 250)
    float* loss = (float*)d_out;

    hipMemsetAsync(loss, 0, (size_t)out_size * sizeof(float), stream);

    region_loss_fused<<<dim3(4, NBB), dim3(1024), 0, stream>>>(
        out_p, tgt_p, loss);
}

// Round 6
// 219.346 us; speedup vs baseline: 1.0433x; 1.0357x over previous
//
#include <hip/hip_runtime.h>
#include <math.h>

#define NBB 128
#define NAA 5
#define NCC 80
#define NHH 28
#define NWW 28
#define NTT 50
#define CH  85            // 5 + NC
#define HW  784           // NH*NW
#define CELLS 3920        // NA*NH*NW

__constant__ float c_AW[5] = {2.8f, 5.1f, 6.4f, 9.2f, 14.1f};
__constant__ float c_AH[5] = {4.8f, 10.2f, 16.3f, 19.8f, 23.7f};

__device__ __forceinline__ float sigmoidf_(float x) {
    return 1.0f / (1.0f + __expf(-x));
}

__device__ __forceinline__ float smooth_l1(float d) {
    float ad = fabsf(d);
    return (ad < 1.0f) ? 0.5f * d * d : ad - 0.5f;
}

// ---------------------------------------------------------------------------
// Fused kernel v5 = v2 (222.1 us, best measured) + ONE subtractive edit:
// the 50-iter assigned-cell scan (ctS b64 read + 3 VALU per iter) is replaced
// by the tcA scatter grid (validated in v3/v4): init -1, dedup'd last-winner
// scatter, ONE b32 gather per cell after the j-loop.
// j-loop LDS traffic: b128+b32+b64 -> b128+b32 per iteration.
// Everything else is byte-identical to v2: grid (4,NB), block 1024 (16 waves,
// 32 waves/CU), stage-3 one record per wave, shuffle reduce, single atomic.
// ---------------------------------------------------------------------------
__global__ __launch_bounds__(1024) void region_loss_fused(
    const float* __restrict__ out, const float* __restrict__ tgt,
    float* __restrict__ d_out)
{
    __shared__ float  tcA[CELLS];     // scatter grid: tconf of last-winner, else -1
    __shared__ float4 boxS[NTT];      // (L, R, T, B)
    __shared__ float  s6[NTT];        // 0.375 * gt area
    __shared__ int    rCell[NTT];
    __shared__ float  rTx[NTT], rTy[NTT], rTw[NTT], rTh[NTT];
    __shared__ int    rCls[NTT];
    __shared__ unsigned char rActive[NTT];
    __shared__ float  wred[16];

    const int b   = blockIdx.y;
    const int bx  = blockIdx.x;
    const int tid = threadIdx.x;

    // ---- init scatter grid (4 iters/thread at 1024 threads) ----
    for (int i = tid; i < CELLS; i += 1024) tcA[i] = -1.0f;

    // ---- Stage 1: per-target prep (threads 0..49) ----
    float myTc = 0.0f;
    int   myCell = -1;
    if (tid < NTT) {
        const float* tp = tgt + b * NTT * 5 + tid * 5;
        float cls = tp[0];
        float gx = tp[1] * NWW;
        float gy = tp[2] * NHH;
        float gw = tp[3] * NWW;
        float gh = tp[4] * NHH;
        float ga = gw * gh;

        boxS[tid] = make_float4(gx - gw * 0.5f, gx + gw * 0.5f,
                                gy - gh * 0.5f, gy + gh * 0.5f);
        s6[tid] = 0.375f * ga;        // 0.6/1.6 = 0.375 exactly

        // best anchor: IoU of (0,0,gw,gh) vs (0,0,aw,ah); first max wins
        int best = 0; float bestI = -1.0f;
        #pragma unroll
        for (int a = 0; a < 5; ++a) {
            float inter = fminf(gw, c_AW[a]) * fminf(gh, c_AH[a]);
            float uni   = ga + c_AW[a] * c_AH[a] - inter;
            float iou   = inter / uni;
            if (iou > bestI) { bestI = iou; best = a; }
        }
        int gi = (int)floorf(gx);
        int gj = (int)floorf(gy);
        int cell = (best * NHH + gj) * NWW + gi;

        // assigned predicted box (4 gathered loads)
        const float* op = out + ((size_t)(b * NAA + best) * CH) * HW + gj * NWW + gi;
        float px = sigmoidf_(op[0])      + (float)gi;
        float py = sigmoidf_(op[HW])     + (float)gj;
        float pw = __expf(op[2 * HW]) * c_AW[best];
        float ph = __expf(op[3 * HW]) * c_AH[best];

        float mx = fminf(px - pw * 0.5f, gx - gw * 0.5f);
        float Mx = fmaxf(px + pw * 0.5f, gx + gw * 0.5f);
        float my = fminf(py - ph * 0.5f, gy - gh * 0.5f);
        float My = fmaxf(py + ph * 0.5f, gy + gh * 0.5f);
        float cw  = pw + gw - (Mx - mx);
        float chh = ph + gh - (My - my);
        float inter = (cw > 0.f && chh > 0.f) ? cw * chh : 0.f;
        float uni   = pw * ph + ga - inter;

        myCell = cell;
        myTc   = inter / uni;
        rCell[tid] = cell;
        rTx[tid]   = gx - (float)gi;
        rTy[tid]   = gy - (float)gj;
        rTw[tid]   = __logf(gw / c_AW[best]);
        rTh[tid]   = __logf(gh / c_AH[best]);
        rCls[tid]  = (int)cls;
    }
    __syncthreads();

    // ---- dedup (last-write-wins) + scatter tconf into grid ----
    if (tid < NTT) {
        unsigned char active = 1;
        for (int t2 = tid + 1; t2 < NTT; ++t2)
            if (rCell[t2] == myCell) active = 0;   // later record wins
        rActive[tid] = active;
        if (active) tcA[myCell] = myTc;            // unique per cell: race-free
    }
    __syncthreads();

    // ---- Stage 2: conf loss over cells (sigil loop, LDS b128+b32/iter) ----
    const int cell = bx * 1024 + tid;
    float term = 0.0f;

    if (cell < CELLS) {
        int a  = cell / HW;
        int hw = cell - a * HW;
        int wi = hw % NWW;
        int hj = hw / NWW;
        const float* op = out + ((size_t)(b * NAA + a) * CH) * HW + hw;

        float px   = sigmoidf_(op[0])  + (float)wi;
        float py   = sigmoidf_(op[HW]) + (float)hj;
        float pw   = __expf(op[2 * HW]) * c_AW[a];
        float ph   = __expf(op[3 * HW]) * c_AH[a];
        float conf = sigmoidf_(op[4 * HW]);

        float l1 = px - pw * 0.5f, r1 = px + pw * 0.5f;
        float t1 = py - ph * 0.5f, b1 = py + ph * 0.5f;
        float c1 = 0.375f * (pw * ph);

        bool flag = false;
        #pragma unroll 5
        for (int j = 0; j < NTT; ++j) {
            float4 bxj = boxS[j];                             // ds_read_b128
            float cw  = fminf(r1, bxj.y) - fmaxf(l1, bxj.x);
            float ch2 = fminf(b1, bxj.w) - fmaxf(t1, bxj.z);
            float inter = fmaxf(cw, 0.f) * fmaxf(ch2, 0.f);
            flag = flag || (inter > c1 + s6[j]);              // iou > 0.6
        }

        float tc = tcA[cell];                                 // one b32 gather
        if (tc > -0.5f) {
            float d = conf - tc; term = 2.5f * d * d;
        } else if (!flag) {
            term = 0.5f * conf * conf;
        }
    }

    // ---- Stage 3: assigned-cell loss, one record per wave ----
    const int wave = tid >> 6;
    const int lane = tid & 63;
    const int j3   = bx * 16 + wave;   // 4*16 = 64 slots >= NTT

    float contrib = 0.0f;

    if (j3 < NTT && rActive[j3]) {
        int rc = rCell[j3];
        int a  = rc / HW;
        int hw = rc - a * HW;
        const float* op = out + ((size_t)(b * NAA + a) * CH) * HW + hw;

        // class logits: lane -> c=lane, plus c=64+lane for lane<16
        float l0  = op[(5 + lane) * HW];
        float l1c = (lane < 16) ? op[(5 + 64 + lane) * HW] : -INFINITY;

        float m = fmaxf(l0, l1c);
        for (int o = 32; o >= 1; o >>= 1) m = fmaxf(m, __shfl_xor(m, o));
        float s = __expf(l0 - m) + ((lane < 16) ? __expf(l1c - m) : 0.0f);
        for (int o = 32; o >= 1; o >>= 1) s += __shfl_xor(s, o);

        int t = rCls[j3];                             // wave-uniform
        float lt = (t < 64) ? __shfl(l0, t) : __shfl(l1c, t - 64);
        float logpt = lt - m - __logf(s);
        float pt = __expf(logpt);
        float focal = -(1.0f - pt) * (1.0f - pt) * logpt;

        if (lane == 0) {
            float x = sigmoidf_(op[0]);
            float y = sigmoidf_(op[HW]);
            float w = op[2 * HW];
            float h = op[3 * HW];
            contrib = focal +
                      0.5f * (smooth_l1(x - rTx[j3]) + smooth_l1(y - rTy[j3]) +
                              smooth_l1(w - rTw[j3]) + smooth_l1(h - rTh[j3]));
        }
    }

    // ---- reduction: wave shuffle + 16-slot LDS + single atomic ----
    float v = term + contrib;                      // contrib nonzero only on lane 0
    #pragma unroll
    for (int o = 32; o >= 1; o >>= 1) v += __shfl_xor(v, o);
    if (lane == 0) wred[wave] = v;
    __syncthreads();
    if (tid == 0) {
        float s = 0.0f;
        #pragma unroll
        for (int w2 = 0; w2 < 16; ++w2) s += wred[w2];
        atomicAdd(d_out, s);
    }
}

extern "C" void kernel_launch(void* const* d_in, const int* in_sizes, int n_in,
                              void* d_out, int out_size, void* d_ws, size_t ws_size,
                              hipStream_t stream) {
    const float* out_p = (const float*)d_in[0];   // (128, 425, 28, 28)
    const float* tgt_p = (const float*)d_in[1];   // (128, 250)
    float* loss = (float*)d_out;

    hipMemsetAsync(loss, 0, (size_t)out_size * sizeof(float), stream);

    region_loss_fused<<<dim3(4, NBB), dim3(1024), 0, stream>>>(
        out_p, tgt_p, loss);
}